// Round 19
// baseline (97.812 us; speedup 1.0000x reference)
//
#include <hip/hip_runtime.h>
#include <stdint.h>

#define B_   32
#define CIN  128
#define HH   56
#define WW   56
#define COUT 256
#define QDIV 7.5f

#define NBLK_AX 2048
#define NBLK_AW 288
#define NBLK_QX (B_ * HH)   // 1792
#define NBLK_QW 288

#define NSLOT 66
#define CSTRIDE (NSLOT * 16)       // 1056 B per ci-16-chunk
#define ROWB (8 * CSTRIDE)         // 8448 B per image row
#define XLDS (4 * ROWB)            // 33792 (rows h0-1..h0+2)
#define WSTEP 16384                // 256 co x 64 ci, one K64 step
#define LDS_TOTAL (XLDS + 2 * WSTEP)   // 66560 -> 2 blocks/CU, 16 waves/CU

typedef int v4i  __attribute__((ext_vector_type(4)));

typedef __attribute__((address_space(3))) unsigned char lds_u8;
typedef __attribute__((address_space(1))) const unsigned char glb_u8;

__device__ __forceinline__ void load_lds16(const void* g, void* l) {
    __builtin_amdgcn_global_load_lds((glb_u8*)g, (lds_u8*)l, 16, 0, 0);
}

__device__ __forceinline__ int q8(float v, float s) {
    return ((int)fminf(fmaxf(rintf(v / s), -8.f), 7.f)) & 0xFF;
}

// ---------- absmax: blocks [0,2048) -> x, [2048,2336) -> w ----------
__global__ __launch_bounds__(256) void absmax_all_kernel(const float* __restrict__ x,
                                                         const float* __restrict__ w,
                                                         unsigned* __restrict__ mbits) {
    const float* p; int n4, i, stride; unsigned* slot;
    if (blockIdx.x < NBLK_AX) {
        p = x; n4 = B_ * CIN * HH * WW / 4;
        i = blockIdx.x * 256 + threadIdx.x; stride = NBLK_AX * 256; slot = mbits;
    } else {
        p = w; n4 = COUT * CIN * 9 / 4;
        i = (blockIdx.x - NBLK_AX) * 256 + threadIdx.x; stride = NBLK_AW * 256; slot = mbits + 1;
    }
    float m = 0.f;
    for (; i < n4; i += stride) {
        float4 v = ((const float4*)p)[i];
        m = fmaxf(m, fmaxf(fmaxf(fabsf(v.x), fabsf(v.y)),
                           fmaxf(fabsf(v.z), fabsf(v.w))));
    }
    #pragma unroll
    for (int off = 32; off; off >>= 1) m = fmaxf(m, __shfl_down(m, off));
    __shared__ float red[4];
    int lane = threadIdx.x & 63, wv = threadIdx.x >> 6;
    if (lane == 0) red[wv] = m;
    __syncthreads();
    if (threadIdx.x == 0) {
        m = fmaxf(fmaxf(red[0], red[1]), fmaxf(red[2], red[3]));
        atomicMax(slot, __float_as_uint(m));
    }
}

// ---------- quantize: x blocks, w blocks, + 1 zero-row block ----------
// qx: per (b,h) row of 8448 B: byte = c*1056 + s*16 + j; slot s in [1,56] holds
//     pixel w = s-1, ci = c*16+j; slots 0 and 57..65 zero.
// qw3 (step-major): byte = s*16384 + g*4096 + m*1024 + jh*256 + co16*16 + jl
//   co = g*64 + m*16 + co16; step s: tap t = s>>1 (kh=t/3,kw=t%3), half hf = s&1;
//   ci = hf*64 + jh*16 + jl.  A-frag(g,s,m) = stepbase + g*4096 + m*1024 + lane*16.
__global__ __launch_bounds__(256) void quant_all_kernel(const float* __restrict__ x,
                                                        const float* __restrict__ w,
                                                        signed char* __restrict__ qx,
                                                        int* __restrict__ qw,
                                                        signed char* __restrict__ qxzero,
                                                        const unsigned* __restrict__ mbits) {
    if (blockIdx.x < NBLK_QX) {
        __shared__ int tile32[WW * 33];               // [w][33 ci-quad dwords]
        const int bh = blockIdx.x;
        const int b = bh / HH, h = bh % HH;
        const float s = __uint_as_float(mbits[0]) / QDIV;
        const float* src = x + (size_t)b * (CIN * HH * WW) + (size_t)h * WW;

        for (int it = threadIdx.x; it < 448; it += 256) {   // 32 ci-quads x 14 w-quads
            const int cq = it / 14, wq = it - cq * 14;
            const float* r0 = src + (size_t)(cq * 4 + 0) * (HH * WW);
            const float* r1 = src + (size_t)(cq * 4 + 1) * (HH * WW);
            const float* r2 = src + (size_t)(cq * 4 + 2) * (HH * WW);
            const float* r3 = src + (size_t)(cq * 4 + 3) * (HH * WW);
            const float4 v0 = ((const float4*)r0)[wq];
            const float4 v1 = ((const float4*)r1)[wq];
            const float4 v2 = ((const float4*)r2)[wq];
            const float4 v3 = ((const float4*)r3)[wq];
            int* tp = &tile32[(wq * 4) * 33 + cq];
            tp[0]  = q8(v0.x, s) | (q8(v1.x, s) << 8) | (q8(v2.x, s) << 16) | (q8(v3.x, s) << 24);
            tp[33] = q8(v0.y, s) | (q8(v1.y, s) << 8) | (q8(v2.y, s) << 16) | (q8(v3.y, s) << 24);
            tp[66] = q8(v0.z, s) | (q8(v1.z, s) << 8) | (q8(v2.z, s) << 16) | (q8(v3.z, s) << 24);
            tp[99] = q8(v0.w, s) | (q8(v1.w, s) << 8) | (q8(v2.w, s) << 16) | (q8(v3.w, s) << 24);
        }
        __syncthreads();
        int4* dst = (int4*)(qx + (size_t)bh * ROWB);
        #pragma unroll
        for (int i = 0; i < 3; ++i) {                 // 528 int4 units
            int u = threadIdx.x + i * 256;
            if (u < 528) {
                int c = u / NSLOT, s2 = u - c * NSLOT;
                int4 v = int4{0, 0, 0, 0};
                if (s2 >= 1 && s2 <= WW) {
                    const int* tp = &tile32[(s2 - 1) * 33 + c * 4];
                    v.x = tp[0]; v.y = tp[1]; v.z = tp[2]; v.w = tp[3];
                }
                dst[u] = v;
            }
        }
    } else if (blockIdx.x < NBLK_QX + NBLK_QW) {
        int d = (blockIdx.x - NBLK_QX) * 256 + threadIdx.x;  // 73728 dwords
        int s9 = d >> 12;                 // step 0..17
        int u  = d & 4095;
        int g    = u >> 10;
        int q9   = u & 1023;
        int m    = q9 >> 8;
        int jh   = (q9 >> 6) & 3;
        int co16 = (q9 >> 2) & 15;
        int jl4  = q9 & 3;
        int co = g * 64 + m * 16 + co16;
        int t = s9 >> 1, hf = s9 & 1;
        int kh = t / 3, kw = t - kh * 3;
        float s = __uint_as_float(mbits[1]) / QDIV;
        int pack = 0;
        #pragma unroll
        for (int j = 0; j < 4; ++j) {
            int ci = hf * 64 + jh * 16 + jl4 * 4 + j;
            float v = w[(((size_t)co * CIN + ci) * 3 + kh) * 3 + kw];
            pack |= q8(v, s) << (8 * j);
        }
        qw[d] = pack;
    } else {
        for (int d = threadIdx.x; d < ROWB / 16; d += 256)
            ((int4*)qxzero)[d] = int4{0, 0, 0, 0};
    }
}

// ---------- conv: 16x16x64 i8 MFMA, 4 waves/SIMD, 2:1 MFMA:ds ratio ----------
// Block: 512 thr / 8 waves; 256 co x 2 rows. Wave (wg=wid&3: 64-co group,
// wrow=wid>>2: row) = 64co x 64px(56 valid), acc[4][4] (64 regs, <=128 total).
// LDS: x rows h0-1..h0+2 (33.8 KB) + weight dbuf 2x16KB = 66.5 KB ->
// 2 blocks/CU = 16 waves/CU = 4 waves/SIMD. Per K64 step: 4 A + 4 B
// ds_read_b128 + 16 MFMA; one __syncthreads per step.
__global__ __launch_bounds__(512, 4) void conv_mfma_kernel(
        const signed char* __restrict__ qxz,   // [zero row | qx rows]
        const signed char* __restrict__ qw3,
        const unsigned* __restrict__ mbits,
        const float* __restrict__ bias,
        float* __restrict__ out) {
    __shared__ signed char lds[LDS_TOTAL];
    signed char* xlds = lds;
    signed char* wlds = lds + XLDS;

    // XCD-chunked swizzle (896 % 8 == 0 -> bijective)
    const int sbid = (blockIdx.x & 7) * 112 + (blockIdx.x >> 3);
    const int b  = sbid / 28;
    const int h0 = (sbid % 28) * 2;

    const int tid  = threadIdx.x;
    const int wid  = tid >> 6;
    const int lane = tid & 63;
    const int l15  = lane & 15;
    const int l4h  = lane >> 4;
    const int wg   = wid & 3;         // 64-co group
    const int wrow = wid >> 2;        // output row 0/1

    // ---- prologue: weight step 0 (16 KB) + x rows h0-1..h0+2 (2112 units) ----
    load_lds16(qw3 + tid * 16,        wlds + tid * 16);
    load_lds16(qw3 + 8192 + tid * 16, wlds + 8192 + tid * 16);
    #pragma unroll
    for (int i = 0; i < 5; ++i) {
        const int u = tid + i * 512;
        if (u < 2112) {
            const int r = u / 528, c = u - r * 528;
            const int hy = h0 - 1 + r;
            const signed char* src = (hy >= 0 && hy < HH)
                ? qxz + (size_t)(1 + b * HH + hy) * ROWB + c * 16
                : qxz + c * 16;
            load_lds16(src, xlds + u * 16);
        }
    }
    __syncthreads();

    v4i acc[4][4];
    #pragma unroll
    for (int m = 0; m < 4; ++m)
        #pragma unroll
        for (int p = 0; p < 4; ++p)
            #pragma unroll
            for (int r = 0; r < 4; ++r) acc[m][p][r] = 0;

    #pragma unroll
    for (int s = 0; s < 18; ++s) {
        if (s < 17) {   // stage next step (16 KB): two 16B loads per thread
            const signed char* gs = qw3 + (s + 1) * WSTEP + tid * 16;
            signed char* ld = wlds + ((s + 1) & 1) * WSTEP + tid * 16;
            load_lds16(gs, ld);
            load_lds16(gs + 8192, ld + 8192);
        }

        const int t = s >> 1, hf = s & 1;
        const int kh = t / 3, kw = t - kh * 3;
        const signed char* ap = wlds + (s & 1) * WSTEP + wg * 4096 + lane * 16;
        const v4i A0 = *(const v4i*)(ap);
        const v4i A1 = *(const v4i*)(ap + 1024);
        const v4i A2 = *(const v4i*)(ap + 2048);
        const v4i A3 = *(const v4i*)(ap + 3072);
        const signed char* xp = xlds + (wrow + kh) * ROWB
                                + (hf * 4 + l4h) * CSTRIDE + (l15 + kw) * 16;
        const v4i B0 = *(const v4i*)(xp);
        const v4i B1 = *(const v4i*)(xp + 256);
        const v4i B2 = *(const v4i*)(xp + 512);
        const v4i B3 = *(const v4i*)(xp + 768);

        acc[0][0] = __builtin_amdgcn_mfma_i32_16x16x64_i8(A0, B0, acc[0][0], 0, 0, 0);
        acc[1][0] = __builtin_amdgcn_mfma_i32_16x16x64_i8(A1, B0, acc[1][0], 0, 0, 0);
        acc[2][0] = __builtin_amdgcn_mfma_i32_16x16x64_i8(A2, B0, acc[2][0], 0, 0, 0);
        acc[3][0] = __builtin_amdgcn_mfma_i32_16x16x64_i8(A3, B0, acc[3][0], 0, 0, 0);
        acc[0][1] = __builtin_amdgcn_mfma_i32_16x16x64_i8(A0, B1, acc[0][1], 0, 0, 0);
        acc[1][1] = __builtin_amdgcn_mfma_i32_16x16x64_i8(A1, B1, acc[1][1], 0, 0, 0);
        acc[2][1] = __builtin_amdgcn_mfma_i32_16x16x64_i8(A2, B1, acc[2][1], 0, 0, 0);
        acc[3][1] = __builtin_amdgcn_mfma_i32_16x16x64_i8(A3, B1, acc[3][1], 0, 0, 0);
        acc[0][2] = __builtin_amdgcn_mfma_i32_16x16x64_i8(A0, B2, acc[0][2], 0, 0, 0);
        acc[1][2] = __builtin_amdgcn_mfma_i32_16x16x64_i8(A1, B2, acc[1][2], 0, 0, 0);
        acc[2][2] = __builtin_amdgcn_mfma_i32_16x16x64_i8(A2, B2, acc[2][2], 0, 0, 0);
        acc[3][2] = __builtin_amdgcn_mfma_i32_16x16x64_i8(A3, B2, acc[3][2], 0, 0, 0);
        acc[0][3] = __builtin_amdgcn_mfma_i32_16x16x64_i8(A0, B3, acc[0][3], 0, 0, 0);
        acc[1][3] = __builtin_amdgcn_mfma_i32_16x16x64_i8(A1, B3, acc[1][3], 0, 0, 0);
        acc[2][3] = __builtin_amdgcn_mfma_i32_16x16x64_i8(A2, B3, acc[2][3], 0, 0, 0);
        acc[3][3] = __builtin_amdgcn_mfma_i32_16x16x64_i8(A3, B3, acc[3][3], 0, 0, 0);

        if (s < 17) __syncthreads();
    }

    // ---- epilogue: dequant + bias; C map: col(px)=l15, row(co)=l4h*4+r ----
    const float sc = (__uint_as_float(mbits[0]) / QDIV) *
                     (__uint_as_float(mbits[1]) / QDIV);
    const int hrow = h0 + wrow;
    #pragma unroll
    for (int m = 0; m < 4; ++m) {
        #pragma unroll
        for (int r = 0; r < 4; ++r) {
            const int co = wg * 64 + m * 16 + l4h * 4 + r;
            const float bv = bias[co];
            float* orow = out + ((size_t)(b * COUT + co) * HH + hrow) * WW;
            orow[l15]      = (float)acc[m][0][r] * sc + bv;
            orow[16 + l15] = (float)acc[m][1][r] * sc + bv;
            orow[32 + l15] = (float)acc[m][2][r] * sc + bv;
            if (l15 < 8) orow[48 + l15] = (float)acc[m][3][r] * sc + bv;
        }
    }
}

extern "C" void kernel_launch(void* const* d_in, const int* in_sizes, int n_in,
                              void* d_out, int out_size, void* d_ws, size_t ws_size,
                              hipStream_t stream) {
    const float* x    = (const float*)d_in[0];
    const float* w    = (const float*)d_in[1];
    const float* bias = (const float*)d_in[2];
    float* out = (float*)d_out;

    unsigned* mbits = (unsigned*)d_ws;
    signed char* qxz = (signed char*)d_ws + 256;     // [zero row | qx rows]
    signed char* qx  = qxz + ROWB;
    signed char* qw3 = qx + (size_t)B_ * HH * ROWB;

    hipMemsetAsync(d_ws, 0, 8, stream);              // mbits only
    hipLaunchKernelGGL(absmax_all_kernel, dim3(NBLK_AX + NBLK_AW), dim3(256), 0, stream,
                       x, w, mbits);
    hipLaunchKernelGGL(quant_all_kernel, dim3(NBLK_QX + NBLK_QW + 1), dim3(256), 0, stream,
                       x, w, qx, (int*)qw3, qxz, mbits);
    hipLaunchKernelGGL(conv_mfma_kernel, dim3(B_ * 28), dim3(512), 0, stream,
                       qxz, qw3, mbits, bias, out);
}

// Round 20
// 97.073 us; speedup vs baseline: 1.0076x; 1.0076x over previous
//
#include <hip/hip_runtime.h>
#include <stdint.h>

#define B_   32
#define CIN  128
#define HH   56
#define WW   56
#define COUT 256
#define QDIV 7.5f
#define HW   (HH * WW)              // 3136

#define NBLK_AX 2048
#define NBLK_AW 288
#define NBLK_QX (B_ * HH)   // 1792
#define NBLK_QW 288

#define NSLOT 66
#define CSTRIDE (NSLOT * 16)       // 1056 B per ci-16-chunk
#define ROWB (8 * CSTRIDE)         // 8448 B per image row
#define XLDS (4 * ROWB)            // 33792 (rows h0-1..h0+2)
#define WSTEP 8192                 // 128 co x 64 ci, one K64 step
#define LDS_TOTAL (XLDS + 2 * WSTEP)   // 50176 -> 3 blocks/CU
#define WGRP 73728                 // 72 KB weights per 64-co group (18 steps * 4 KB)

typedef int v4i  __attribute__((ext_vector_type(4)));

typedef __attribute__((address_space(3))) unsigned char lds_u8;
typedef __attribute__((address_space(1))) const unsigned char glb_u8;

__device__ __forceinline__ void load_lds16(const void* g, void* l) {
    __builtin_amdgcn_global_load_lds((glb_u8*)g, (lds_u8*)l, 16, 0, 0);
}

__device__ __forceinline__ int q8(float v, float s) {
    return ((int)fminf(fmaxf(rintf(v / s), -8.f), 7.f)) & 0xFF;
}

// ---------- absmax: per-block partial maxima (no atomics, no init) ----------
// blocks [0,2048) -> pmax_x[bid]; [2048,2336) -> pmax_w[bid-2048]
__global__ __launch_bounds__(256) void absmax_all_kernel(const float* __restrict__ x,
                                                         const float* __restrict__ w,
                                                         float* __restrict__ pmax_x,
                                                         float* __restrict__ pmax_w) {
    const float* p; int n4, i, stride;
    if (blockIdx.x < NBLK_AX) {
        p = x; n4 = B_ * CIN * HW / 4;
        i = blockIdx.x * 256 + threadIdx.x; stride = NBLK_AX * 256;
    } else {
        p = w; n4 = COUT * CIN * 9 / 4;
        i = (blockIdx.x - NBLK_AX) * 256 + threadIdx.x; stride = NBLK_AW * 256;
    }
    float m = 0.f;
    for (; i < n4; i += stride) {
        float4 v = ((const float4*)p)[i];
        m = fmaxf(m, fmaxf(fmaxf(fabsf(v.x), fabsf(v.y)),
                           fmaxf(fabsf(v.z), fabsf(v.w))));
    }
    #pragma unroll
    for (int off = 32; off; off >>= 1) m = fmaxf(m, __shfl_down(m, off));
    __shared__ float red[4];
    int lane = threadIdx.x & 63, wv = threadIdx.x >> 6;
    if (lane == 0) red[wv] = m;
    __syncthreads();
    if (threadIdx.x == 0) {
        m = fmaxf(fmaxf(red[0], red[1]), fmaxf(red[2], red[3]));
        if (blockIdx.x < NBLK_AX) pmax_x[blockIdx.x] = m;
        else                      pmax_w[blockIdx.x - NBLK_AX] = m;
    }
}

// reduce partials -> scale (all threads get the value; one barrier)
__device__ __forceinline__ float reduce_scale(const float* __restrict__ pm, int n,
                                              float* red) {
    float m = 0.f;
    for (int i = threadIdx.x; i < n; i += 256) m = fmaxf(m, pm[i]);
    #pragma unroll
    for (int off = 32; off; off >>= 1) m = fmaxf(m, __shfl_down(m, off));
    int lane = threadIdx.x & 63, wv = threadIdx.x >> 6;
    if (lane == 0) red[wv] = m;
    __syncthreads();
    return fmaxf(fmaxf(red[0], red[1]), fmaxf(red[2], red[3])) / QDIV;
}

// ---------- quantize: x blocks (LDS-free pack), w blocks, + 1 zero-row block ----------
// qx: per (b,h) row of 8448 B: byte = c*1056 + s*16 + j; slot s in [1,56] holds
//     pixel w = s-1, ci = c*16+j; slots 0 and 57..65 zero.
// qw3: byte = g*73728 + s*4096 + m*1024 + jh*256 + co16*16 + jl
//   co = g*64 + m*16 + co16; step s: tap t = s>>1 (kh=t/3,kw=t%3), half hf = s&1;
//   ci = hf*64 + jh*16 + jl.
__global__ __launch_bounds__(256) void quant_all_kernel(const float* __restrict__ x,
                                                        const float* __restrict__ w,
                                                        signed char* __restrict__ qx,
                                                        int* __restrict__ qw,
                                                        signed char* __restrict__ qxzero,
                                                        const float* __restrict__ pmax_x,
                                                        const float* __restrict__ pmax_w) {
    __shared__ float red[4];
    if (blockIdx.x < NBLK_QX) {
        const float s = reduce_scale(pmax_x, NBLK_AX, red);
        const int bh = blockIdx.x;
        const int b = bh / HH, h = bh % HH;
        const float* src = x + (size_t)b * (CIN * HW) + (size_t)h * WW;
        int4* dst = (int4*)(qx + (size_t)bh * ROWB);
        #pragma unroll
        for (int i = 0; i < 3; ++i) {                 // 528 16B units
            const int u = threadIdx.x + i * 256;
            if (u < 528) {
                const int c = u / NSLOT, s2 = u - c * NSLOT;
                int4 v = int4{0, 0, 0, 0};
                if (s2 >= 1 && s2 <= WW) {
                    const float* col = src + (size_t)(c * 16) * HW + (s2 - 1);
                    v.x = q8(col[0], s)       | (q8(col[HW], s) << 8)
                        | (q8(col[2*HW], s) << 16) | (q8(col[3*HW], s) << 24);
                    v.y = q8(col[4*HW], s)    | (q8(col[5*HW], s) << 8)
                        | (q8(col[6*HW], s) << 16) | (q8(col[7*HW], s) << 24);
                    v.z = q8(col[8*HW], s)    | (q8(col[9*HW], s) << 8)
                        | (q8(col[10*HW], s) << 16)| (q8(col[11*HW], s) << 24);
                    v.w = q8(col[12*HW], s)   | (q8(col[13*HW], s) << 8)
                        | (q8(col[14*HW], s) << 16)| (q8(col[15*HW], s) << 24);
                }
                dst[u] = v;
            }
        }
    } else if (blockIdx.x < NBLK_QX + NBLK_QW) {
        const float s = reduce_scale(pmax_w, NBLK_AW, red);
        int d = (blockIdx.x - NBLK_QX) * 256 + threadIdx.x;  // 73728 dwords
        int g  = d / 18432;
        int r1 = d - g * 18432;
        int s9 = r1 >> 10;                // step 0..17
        int u  = r1 & 1023;
        int m    = u >> 8;
        int jh   = (u >> 6) & 3;
        int co16 = (u >> 2) & 15;
        int jl4  = u & 3;
        int co = g * 64 + m * 16 + co16;
        int t = s9 >> 1, hf = s9 & 1;
        int kh = t / 3, kw = t - kh * 3;
        int pack = 0;
        #pragma unroll
        for (int j = 0; j < 4; ++j) {
            int ci = hf * 64 + jh * 16 + jl4 * 4 + j;
            float v = w[(((size_t)co * CIN + ci) * 3 + kh) * 3 + kw];
            pack |= q8(v, s) << (8 * j);
        }
        qw[d] = pack;
    } else {
        for (int d = threadIdx.x; d < ROWB / 16; d += 256)
            ((int4*)qxzero)[d] = int4{0, 0, 0, 0};
    }
}

// ---------- conv: 16x16x64 i8 MFMA, B-hoisted reg dbuf + setprio (r18) ----------
__global__ __launch_bounds__(256, 3) void conv_mfma_kernel(
        const signed char* __restrict__ qxz,   // [zero row | qx rows]
        const signed char* __restrict__ qw3,
        const float* __restrict__ pmax_x,
        const float* __restrict__ pmax_w,
        const float* __restrict__ bias,
        float* __restrict__ out) {
    __shared__ signed char lds[LDS_TOTAL];
    signed char* xlds = lds;
    signed char* wlds = lds + XLDS;

    // XCD-chunked swizzle (1792 % 8 == 0 -> bijective); ch fastest in a chunk
    const int sbid = (blockIdx.x & 7) * 224 + (blockIdx.x >> 3);
    const int ch   = sbid & 1;        // co half (128 co)
    const int brg  = sbid >> 1;       // 0..895
    const int rg   = brg % 28;
    const int b    = brg / 28;
    const int h0   = rg * 2;

    const int tid  = threadIdx.x;
    const int wid  = tid >> 6;
    const int lane = tid & 63;
    const int l15  = lane & 15;
    const int l4h  = lane >> 4;
    const int wg   = wid & 1;         // 64-co group within the half
    const int wrow = wid >> 1;        // output row 0/1

    const signed char* wsrc = qw3 + (size_t)(ch * 2 + (tid >> 7)) * WGRP + (tid & 127) * 16;
    signed char* wdst = wlds + (tid >> 7) * 4096 + (tid & 127) * 16;

    // ---- prologue: weight step 0 + x rows h0-1..h0+2 (2112 16B units) ----
    load_lds16(wsrc, wdst);
    load_lds16(wsrc + 2048, wdst + 2048);
    #pragma unroll
    for (int i = 0; i < 9; ++i) {
        const int u = tid + i * 256;
        if (u < 2112) {
            const int r = u / 528, c = u - r * 528;
            const int hy = h0 - 1 + r;
            const signed char* src = (hy >= 0 && hy < HH)
                ? qxz + (size_t)(1 + b * HH + hy) * ROWB + c * 16
                : qxz + c * 16;
            load_lds16(src, xlds + u * 16);
        }
    }
    __syncthreads();

    v4i acc[4][4];
    #pragma unroll
    for (int m = 0; m < 4; ++m)
        #pragma unroll
        for (int p = 0; p < 4; ++p)
            #pragma unroll
            for (int r = 0; r < 4; ++r) acc[m][p][r] = 0;

    v4i Aa[4], Ab[4], Ba[4], Bb[4];
#define RD_A(S, DST)                                                               \
    {                                                                              \
        const signed char* ap_ = wlds + ((S) & 1) * WSTEP + wg * 4096 + lane * 16; \
        DST[0] = *(const v4i*)(ap_);                                               \
        DST[1] = *(const v4i*)(ap_ + 1024);                                        \
        DST[2] = *(const v4i*)(ap_ + 2048);                                        \
        DST[3] = *(const v4i*)(ap_ + 3072);                                        \
    }
#define RD_B(S, DST)                                                               \
    {                                                                              \
        const int t_ = (S) >> 1, hf_ = (S) & 1;                                    \
        const int kh_ = t_ / 3, kw_ = t_ - kh_ * 3;                                \
        const signed char* xp_ = xlds + (wrow + kh_) * ROWB                        \
                                 + (hf_ * 4 + l4h) * CSTRIDE + (l15 + kw_) * 16;   \
        DST[0] = *(const v4i*)(xp_);                                               \
        DST[1] = *(const v4i*)(xp_ + 256);                                         \
        DST[2] = *(const v4i*)(xp_ + 512);                                         \
        DST[3] = *(const v4i*)(xp_ + 768);                                         \
    }
#define MFMA16(CA, CB)                                                                    \
    {                                                                                     \
        __builtin_amdgcn_s_setprio(1);                                                    \
        _Pragma("unroll")                                                                 \
        for (int p = 0; p < 4; ++p) {                                                     \
            acc[0][p] = __builtin_amdgcn_mfma_i32_16x16x64_i8(CA[0], CB[p], acc[0][p], 0, 0, 0); \
            acc[1][p] = __builtin_amdgcn_mfma_i32_16x16x64_i8(CA[1], CB[p], acc[1][p], 0, 0, 0); \
            acc[2][p] = __builtin_amdgcn_mfma_i32_16x16x64_i8(CA[2], CB[p], acc[2][p], 0, 0, 0); \
            acc[3][p] = __builtin_amdgcn_mfma_i32_16x16x64_i8(CA[3], CB[p], acc[3][p], 0, 0, 0); \
        }                                                                                 \
        __builtin_amdgcn_s_setprio(0);                                                    \
    }
#define STAGE(S)                                                                   \
    {                                                                              \
        load_lds16(wsrc + (S) * 4096,        wdst + ((S) & 1) * WSTEP);            \
        load_lds16(wsrc + (S) * 4096 + 2048, wdst + ((S) & 1) * WSTEP + 2048);     \
    }
#define STEP(S, CA, CB, NA, NB)                                                    \
    {                                                                              \
        if ((S) + 1 < 18) { STAGE((S) + 1) RD_B((S) + 1, NB) }                     \
        MFMA16(CA, CB)                                                             \
        if ((S) + 1 < 18) {                                                        \
            __syncthreads();                                                       \
            RD_A((S) + 1, NA)                                                      \
        }                                                                          \
    }

    RD_A(0, Aa)
    RD_B(0, Ba)
    #pragma unroll
    for (int s2 = 0; s2 < 9; ++s2) {
        STEP(s2 * 2,     Aa, Ba, Ab, Bb)
        STEP(s2 * 2 + 1, Ab, Bb, Aa, Ba)
    }
#undef STEP
#undef STAGE
#undef MFMA16
#undef RD_B
#undef RD_A

    // ---- epilogue: dequant + bias; C map: col(px)=l15, row(co)=l4h*4+r ----
    // scales from partial-max arrays (L2-hot, wave-uniform)
    float mx = 0.f, mw = 0.f;
    // lightweight: lane-parallel over 2048/288 partials within the first wave's scope
    for (int i = lane; i < NBLK_AX; i += 64) mx = fmaxf(mx, pmax_x[i]);
    for (int i = lane; i < NBLK_AW; i += 64) mw = fmaxf(mw, pmax_w[i]);
    #pragma unroll
    for (int off = 32; off; off >>= 1) {
        mx = fmaxf(mx, __shfl_down(mx, off));
        mw = fmaxf(mw, __shfl_down(mw, off));
    }
    mx = __shfl(mx, 0);
    mw = __shfl(mw, 0);
    const float sc = (mx / QDIV) * (mw / QDIV);

    const int hrow = h0 + wrow;
    #pragma unroll
    for (int m = 0; m < 4; ++m) {
        #pragma unroll
        for (int r = 0; r < 4; ++r) {
            const int co = ch * 128 + wg * 64 + m * 16 + l4h * 4 + r;
            const float bv = bias[co];
            float* orow = out + ((size_t)(b * COUT + co) * HH + hrow) * WW;
            orow[l15]      = (float)acc[m][0][r] * sc + bv;
            orow[16 + l15] = (float)acc[m][1][r] * sc + bv;
            orow[32 + l15] = (float)acc[m][2][r] * sc + bv;
            if (l15 < 8) orow[48 + l15] = (float)acc[m][3][r] * sc + bv;
        }
    }
}

extern "C" void kernel_launch(void* const* d_in, const int* in_sizes, int n_in,
                              void* d_out, int out_size, void* d_ws, size_t ws_size,
                              hipStream_t stream) {
    const float* x    = (const float*)d_in[0];
    const float* w    = (const float*)d_in[1];
    const float* bias = (const float*)d_in[2];
    float* out = (float*)d_out;

    float* pmax_x = (float*)d_ws;                    // 2048 floats
    float* pmax_w = (float*)d_ws + 2048;             // 288 floats
    signed char* qxz = (signed char*)d_ws + 16384;   // [zero row | qx rows]
    signed char* qx  = qxz + ROWB;
    signed char* qw3 = qx + (size_t)B_ * HH * ROWB;

    hipLaunchKernelGGL(absmax_all_kernel, dim3(NBLK_AX + NBLK_AW), dim3(256), 0, stream,
                       x, w, pmax_x, pmax_w);
    hipLaunchKernelGGL(quant_all_kernel, dim3(NBLK_QX + NBLK_QW + 1), dim3(256), 0, stream,
                       x, w, qx, (int*)qw3, qxz, pmax_x, pmax_w);
    hipLaunchKernelGGL(conv_mfma_kernel, dim3(B_ * 28 * 2), dim3(256), 0, stream,
                       qxz, qw3, pmax_x, pmax_w, bias, out);
}

// Round 21
// 77.029 us; speedup vs baseline: 1.2698x; 1.2602x over previous
//
#include <hip/hip_runtime.h>
#include <stdint.h>

#define B_   32
#define CIN  128
#define HH   56
#define WW   56
#define COUT 256
#define QDIV 7.5f
#define HW   (HH * WW)              // 3136

#define NBLK_AX 2048
#define NBLK_AW 288
#define NBLK_QX (B_ * HH)   // 1792
#define NBLK_QW 288

#define NSLOT 66
#define CSTRIDE (NSLOT * 16)       // 1056 B per ci-16-chunk
#define ROWB (8 * CSTRIDE)         // 8448 B per image row
#define XLDS (4 * ROWB)            // 33792 (rows h0-1..h0+2)
#define WSTEP 8192                 // 128 co x 64 ci, one K64 step
#define LDS_TOTAL (XLDS + 2 * WSTEP)   // 50176 -> 3 blocks/CU
#define WGRP 73728                 // 72 KB weights per 64-co group (18 steps * 4 KB)

typedef int v4i  __attribute__((ext_vector_type(4)));

typedef __attribute__((address_space(3))) unsigned char lds_u8;
typedef __attribute__((address_space(1))) const unsigned char glb_u8;

__device__ __forceinline__ void load_lds16(const void* g, void* l) {
    __builtin_amdgcn_global_load_lds((glb_u8*)g, (lds_u8*)l, 16, 0, 0);
}

__device__ __forceinline__ int q8(float v, float s) {
    return ((int)fminf(fmaxf(rintf(v / s), -8.f), 7.f)) & 0xFF;
}

// ---------- absmax: per-block partial maxima (no atomics, no init) ----------
__global__ __launch_bounds__(256) void absmax_all_kernel(const float* __restrict__ x,
                                                         const float* __restrict__ w,
                                                         float* __restrict__ pmax_x,
                                                         float* __restrict__ pmax_w) {
    const float* p; int n4, i, stride;
    if (blockIdx.x < NBLK_AX) {
        p = x; n4 = B_ * CIN * HW / 4;
        i = blockIdx.x * 256 + threadIdx.x; stride = NBLK_AX * 256;
    } else {
        p = w; n4 = COUT * CIN * 9 / 4;
        i = (blockIdx.x - NBLK_AX) * 256 + threadIdx.x; stride = NBLK_AW * 256;
    }
    float m = 0.f;
    for (; i < n4; i += stride) {
        float4 v = ((const float4*)p)[i];
        m = fmaxf(m, fmaxf(fmaxf(fabsf(v.x), fabsf(v.y)),
                           fmaxf(fabsf(v.z), fabsf(v.w))));
    }
    #pragma unroll
    for (int off = 32; off; off >>= 1) m = fmaxf(m, __shfl_down(m, off));
    __shared__ float red[4];
    int lane = threadIdx.x & 63, wv = threadIdx.x >> 6;
    if (lane == 0) red[wv] = m;
    __syncthreads();
    if (threadIdx.x == 0) {
        m = fmaxf(fmaxf(red[0], red[1]), fmaxf(red[2], red[3]));
        if (blockIdx.x < NBLK_AX) pmax_x[blockIdx.x] = m;
        else                      pmax_w[blockIdx.x - NBLK_AX] = m;
    }
}

// reduce partials -> scale (all threads get the value; one barrier)
__device__ __forceinline__ float reduce_scale(const float* __restrict__ pm, int n,
                                              float* red) {
    float m = 0.f;
    for (int i = threadIdx.x; i < n; i += 256) m = fmaxf(m, pm[i]);
    #pragma unroll
    for (int off = 32; off; off >>= 1) m = fmaxf(m, __shfl_down(m, off));
    int lane = threadIdx.x & 63, wv = threadIdx.x >> 6;
    if (lane == 0) red[wv] = m;
    __syncthreads();
    return fmaxf(fmaxf(red[0], red[1]), fmaxf(red[2], red[3])) / QDIV;
}

// ---------- quantize: x blocks (LDS-free pack), w blocks, + 1 aux block ----------
// qx: per (b,h) row of 8448 B: byte = c*1056 + s*16 + j; slot s in [1,56] holds
//     pixel w = s-1, ci = c*16+j; slots 0 and 57..65 zero.
// qw3: byte = g*73728 + s*4096 + m*1024 + jh*256 + co16*16 + jl
//   co = g*64 + m*16 + co16; step s: tap t = s>>1, half hf = s&1; ci = hf*64+jh*16+jl.
// aux block: zero border row + publish fused dequant scale.
__global__ __launch_bounds__(256) void quant_all_kernel(const float* __restrict__ x,
                                                        const float* __restrict__ w,
                                                        signed char* __restrict__ qx,
                                                        int* __restrict__ qw,
                                                        signed char* __restrict__ qxzero,
                                                        const float* __restrict__ pmax_x,
                                                        const float* __restrict__ pmax_w,
                                                        float* __restrict__ scales) {
    __shared__ float red[8];
    if (blockIdx.x < NBLK_QX) {
        const float s = reduce_scale(pmax_x, NBLK_AX, red);
        const int bh = blockIdx.x;
        const int b = bh / HH, h = bh % HH;
        const float* src = x + (size_t)b * (CIN * HW) + (size_t)h * WW;
        int4* dst = (int4*)(qx + (size_t)bh * ROWB);
        #pragma unroll
        for (int i = 0; i < 3; ++i) {                 // 528 16B units
            const int u = threadIdx.x + i * 256;
            if (u < 528) {
                const int c = u / NSLOT, s2 = u - c * NSLOT;
                int4 v = int4{0, 0, 0, 0};
                if (s2 >= 1 && s2 <= WW) {
                    const float* col = src + (size_t)(c * 16) * HW + (s2 - 1);
                    v.x = q8(col[0], s)       | (q8(col[HW], s) << 8)
                        | (q8(col[2*HW], s) << 16) | (q8(col[3*HW], s) << 24);
                    v.y = q8(col[4*HW], s)    | (q8(col[5*HW], s) << 8)
                        | (q8(col[6*HW], s) << 16) | (q8(col[7*HW], s) << 24);
                    v.z = q8(col[8*HW], s)    | (q8(col[9*HW], s) << 8)
                        | (q8(col[10*HW], s) << 16)| (q8(col[11*HW], s) << 24);
                    v.w = q8(col[12*HW], s)   | (q8(col[13*HW], s) << 8)
                        | (q8(col[14*HW], s) << 16)| (q8(col[15*HW], s) << 24);
                }
                dst[u] = v;
            }
        }
    } else if (blockIdx.x < NBLK_QX + NBLK_QW) {
        const float s = reduce_scale(pmax_w, NBLK_AW, red);
        int d = (blockIdx.x - NBLK_QX) * 256 + threadIdx.x;  // 73728 dwords
        int g  = d / 18432;
        int r1 = d - g * 18432;
        int s9 = r1 >> 10;                // step 0..17
        int u  = r1 & 1023;
        int m    = u >> 8;
        int jh   = (u >> 6) & 3;
        int co16 = (u >> 2) & 15;
        int jl4  = u & 3;
        int co = g * 64 + m * 16 + co16;
        int t = s9 >> 1, hf = s9 & 1;
        int kh = t / 3, kw = t - kh * 3;
        int pack = 0;
        #pragma unroll
        for (int j = 0; j < 4; ++j) {
            int ci = hf * 64 + jh * 16 + jl4 * 4 + j;
            float v = w[(((size_t)co * CIN + ci) * 3 + kh) * 3 + kw];
            pack |= q8(v, s) << (8 * j);
        }
        qw[d] = pack;
    } else {
        // aux block: zero border row + fused scale
        for (int d = threadIdx.x; d < ROWB / 16; d += 256)
            ((int4*)qxzero)[d] = int4{0, 0, 0, 0};
        float mx = 0.f, mw = 0.f;
        for (int i = threadIdx.x; i < NBLK_AX; i += 256) mx = fmaxf(mx, pmax_x[i]);
        for (int i = threadIdx.x; i < NBLK_AW; i += 256) mw = fmaxf(mw, pmax_w[i]);
        #pragma unroll
        for (int off = 32; off; off >>= 1) {
            mx = fmaxf(mx, __shfl_down(mx, off));
            mw = fmaxf(mw, __shfl_down(mw, off));
        }
        int lane = threadIdx.x & 63, wv = threadIdx.x >> 6;
        if (lane == 0) { red[wv] = mx; red[4 + wv] = mw; }
        __syncthreads();
        if (threadIdx.x == 0) {
            float fx = fmaxf(fmaxf(red[0], red[1]), fmaxf(red[2], red[3]));
            float fw = fmaxf(fmaxf(red[4], red[5]), fmaxf(red[6], red[7]));
            scales[0] = (fx / QDIV) * (fw / QDIV);
        }
    }
}

// ---------- conv: 16x16x64 i8 MFMA, B-hoisted reg dbuf + setprio (r18) ----------
__global__ __launch_bounds__(256, 3) void conv_mfma_kernel(
        const signed char* __restrict__ qxz,   // [zero row | qx rows]
        const signed char* __restrict__ qw3,
        const float* __restrict__ scales,
        const float* __restrict__ bias,
        float* __restrict__ out) {
    __shared__ signed char lds[LDS_TOTAL];
    signed char* xlds = lds;
    signed char* wlds = lds + XLDS;

    // XCD-chunked swizzle (1792 % 8 == 0 -> bijective); ch fastest in a chunk
    const int sbid = (blockIdx.x & 7) * 224 + (blockIdx.x >> 3);
    const int ch   = sbid & 1;        // co half (128 co)
    const int brg  = sbid >> 1;       // 0..895
    const int rg   = brg % 28;
    const int b    = brg / 28;
    const int h0   = rg * 2;

    const int tid  = threadIdx.x;
    const int wid  = tid >> 6;
    const int lane = tid & 63;
    const int l15  = lane & 15;
    const int l4h  = lane >> 4;
    const int wg   = wid & 1;         // 64-co group within the half
    const int wrow = wid >> 1;        // output row 0/1

    const signed char* wsrc = qw3 + (size_t)(ch * 2 + (tid >> 7)) * WGRP + (tid & 127) * 16;
    signed char* wdst = wlds + (tid >> 7) * 4096 + (tid & 127) * 16;

    // ---- prologue: weight step 0 + x rows h0-1..h0+2 (2112 16B units) ----
    load_lds16(wsrc, wdst);
    load_lds16(wsrc + 2048, wdst + 2048);
    #pragma unroll
    for (int i = 0; i < 9; ++i) {
        const int u = tid + i * 256;
        if (u < 2112) {
            const int r = u / 528, c = u - r * 528;
            const int hy = h0 - 1 + r;
            const signed char* src = (hy >= 0 && hy < HH)
                ? qxz + (size_t)(1 + b * HH + hy) * ROWB + c * 16
                : qxz + c * 16;
            load_lds16(src, xlds + u * 16);
        }
    }
    __syncthreads();

    v4i acc[4][4];
    #pragma unroll
    for (int m = 0; m < 4; ++m)
        #pragma unroll
        for (int p = 0; p < 4; ++p)
            #pragma unroll
            for (int r = 0; r < 4; ++r) acc[m][p][r] = 0;

    v4i Aa[4], Ab[4], Ba[4], Bb[4];
#define RD_A(S, DST)                                                               \
    {                                                                              \
        const signed char* ap_ = wlds + ((S) & 1) * WSTEP + wg * 4096 + lane * 16; \
        DST[0] = *(const v4i*)(ap_);                                               \
        DST[1] = *(const v4i*)(ap_ + 1024);                                        \
        DST[2] = *(const v4i*)(ap_ + 2048);                                        \
        DST[3] = *(const v4i*)(ap_ + 3072);                                        \
    }
#define RD_B(S, DST)                                                               \
    {                                                                              \
        const int t_ = (S) >> 1, hf_ = (S) & 1;                                    \
        const int kh_ = t_ / 3, kw_ = t_ - kh_ * 3;                                \
        const signed char* xp_ = xlds + (wrow + kh_) * ROWB                        \
                                 + (hf_ * 4 + l4h) * CSTRIDE + (l15 + kw_) * 16;   \
        DST[0] = *(const v4i*)(xp_);                                               \
        DST[1] = *(const v4i*)(xp_ + 256);                                         \
        DST[2] = *(const v4i*)(xp_ + 512);                                         \
        DST[3] = *(const v4i*)(xp_ + 768);                                         \
    }
#define MFMA16(CA, CB)                                                                    \
    {                                                                                     \
        __builtin_amdgcn_s_setprio(1);                                                    \
        _Pragma("unroll")                                                                 \
        for (int p = 0; p < 4; ++p) {                                                     \
            acc[0][p] = __builtin_amdgcn_mfma_i32_16x16x64_i8(CA[0], CB[p], acc[0][p], 0, 0, 0); \
            acc[1][p] = __builtin_amdgcn_mfma_i32_16x16x64_i8(CA[1], CB[p], acc[1][p], 0, 0, 0); \
            acc[2][p] = __builtin_amdgcn_mfma_i32_16x16x64_i8(CA[2], CB[p], acc[2][p], 0, 0, 0); \
            acc[3][p] = __builtin_amdgcn_mfma_i32_16x16x64_i8(CA[3], CB[p], acc[3][p], 0, 0, 0); \
        }                                                                                 \
        __builtin_amdgcn_s_setprio(0);                                                    \
    }
#define STAGE(S)                                                                   \
    {                                                                              \
        load_lds16(wsrc + (S) * 4096,        wdst + ((S) & 1) * WSTEP);            \
        load_lds16(wsrc + (S) * 4096 + 2048, wdst + ((S) & 1) * WSTEP + 2048);     \
    }
#define STEP(S, CA, CB, NA, NB)                                                    \
    {                                                                              \
        if ((S) + 1 < 18) { STAGE((S) + 1) RD_B((S) + 1, NB) }                     \
        MFMA16(CA, CB)                                                             \
        if ((S) + 1 < 18) {                                                        \
            __syncthreads();                                                       \
            RD_A((S) + 1, NA)                                                      \
        }                                                                          \
    }

    RD_A(0, Aa)
    RD_B(0, Ba)
    #pragma unroll
    for (int s2 = 0; s2 < 9; ++s2) {
        STEP(s2 * 2,     Aa, Ba, Ab, Bb)
        STEP(s2 * 2 + 1, Ab, Bb, Aa, Ba)
    }
#undef STEP
#undef STAGE
#undef MFMA16
#undef RD_B
#undef RD_A

    // ---- epilogue: dequant + bias; C map: col(px)=l15, row(co)=l4h*4+r ----
    const float sc = scales[0];
    const int hrow = h0 + wrow;
    #pragma unroll
    for (int m = 0; m < 4; ++m) {
        #pragma unroll
        for (int r = 0; r < 4; ++r) {
            const int co = ch * 128 + wg * 64 + m * 16 + l4h * 4 + r;
            const float bv = bias[co];
            float* orow = out + ((size_t)(b * COUT + co) * HH + hrow) * WW;
            orow[l15]      = (float)acc[m][0][r] * sc + bv;
            orow[16 + l15] = (float)acc[m][1][r] * sc + bv;
            orow[32 + l15] = (float)acc[m][2][r] * sc + bv;
            if (l15 < 8) orow[48 + l15] = (float)acc[m][3][r] * sc + bv;
        }
    }
}

extern "C" void kernel_launch(void* const* d_in, const int* in_sizes, int n_in,
                              void* d_out, int out_size, void* d_ws, size_t ws_size,
                              hipStream_t stream) {
    const float* x    = (const float*)d_in[0];
    const float* w    = (const float*)d_in[1];
    const float* bias = (const float*)d_in[2];
    float* out = (float*)d_out;

    float* pmax_x = (float*)d_ws;                    // 2048 floats
    float* pmax_w = (float*)d_ws + 2048;             // 288 floats
    float* scales = (float*)d_ws + 2336;             // 1 float (fused sx*sw)
    signed char* qxz = (signed char*)d_ws + 16384;   // [zero row | qx rows]
    signed char* qx  = qxz + ROWB;
    signed char* qw3 = qx + (size_t)B_ * HH * ROWB;

    hipLaunchKernelGGL(absmax_all_kernel, dim3(NBLK_AX + NBLK_AW), dim3(256), 0, stream,
                       x, w, pmax_x, pmax_w);
    hipLaunchKernelGGL(quant_all_kernel, dim3(NBLK_QX + NBLK_QW + 1), dim3(256), 0, stream,
                       x, w, qx, (int*)qw3, qxz, pmax_x, pmax_w, scales);
    hipLaunchKernelGGL(conv_mfma_kernel, dim3(B_ * 28 * 2), dim3(256), 0, stream,
                       qxz, qw3, scales, bias, out);
}